// Round 2
// baseline (281.412 us; speedup 1.0000x reference)
//
#include <hip/hip_runtime.h>
#include <math.h>

// Problem constants (from reference setup_inputs)
constexpr int Bn = 2, Cn = 256, Hn = 200, Wn = 304, Nroi = 1000;
constexpr int OH = 7, OW = 7, SRn = 2;
constexpr int NS = OH * SRn;   // 14 subsample rows/cols
constexpr int NP = NS * NS;    // 196 subsample positions per roi
constexpr int NBIN = OH * OW;  // 49
constexpr int HWn = Hn * Wn;   // 60800
constexpr float SCALE = 0.25f;

// ---------------------------------------------------------------------------
// Per-position sampling descriptor (matches JAX reference arithmetic, f32).
// ---------------------------------------------------------------------------
__device__ __forceinline__ void compute_desc(const float* __restrict__ r, int p,
                                             int& idx, int& dx, int& dyW,
                                             float4& w) {
  float cw = r[1] * SCALE - 0.5f;
  float ch = r[2] * SCALE - 0.5f;
  float rw = r[3] * SCALE;
  float rh = r[4] * SCALE;
  float theta = r[5] * 0.017453292519943295f;  // pi/180
  float cs = cosf(theta), sn = sinf(theta);
  float bin_h = rh * (1.0f / OH);
  float bin_w = rw * (1.0f / OW);
  int ki = p / NS;
  int kj = p - ki * NS;
  float ty = ((float)ki + 0.5f) * (1.0f / SRn);
  float tx = ((float)kj + 0.5f) * (1.0f / SRn);
  float yy = -0.5f * rh + ty * bin_h;
  float xx = -0.5f * rw + tx * bin_w;
  float y = yy * cs - xx * sn + ch;
  float x = yy * sn + xx * cs + cw;
  bool empty = (y < -1.0f) || (y > (float)Hn) || (x < -1.0f) || (x > (float)Wn);
  y = fmaxf(y, 0.0f);
  x = fmaxf(x, 0.0f);
  int yl = min(max((int)floorf(y), 0), Hn - 1);
  int xl = min(max((int)floorf(x), 0), Wn - 1);
  int yh = min(yl + 1, Hn - 1);
  int xh = min(xl + 1, Wn - 1);
  float ly = fminf(fmaxf(y - (float)yl, 0.0f), 1.0f);
  float lx = fminf(fmaxf(x - (float)xl, 0.0f), 1.0f);
  float hy = 1.0f - ly, hx = 1.0f - lx;
  if (empty) {
    w.x = w.y = w.z = w.w = 0.0f;
  } else {
    w.x = hy * hx;
    w.y = hy * lx;
    w.z = ly * hx;
    w.w = ly * lx;
  }
  idx = yl * Wn + xl;
  dx = xh - xl;
  dyW = (yh - yl) * Wn;
}

__device__ __forceinline__ unsigned bf16rne(float f) {
  unsigned u = __float_as_uint(f);
  return (u + 0x7fffu + ((u >> 16) & 1u)) >> 16;
}
__device__ __forceinline__ unsigned bf16pack(float lo, float hi) {
  return bf16rne(lo) | (bf16rne(hi) << 16);
}

// ---------------------------------------------------------------------------
// Kernel 0: spatial sort of roi indices (batch + Morton of 16px center tile).
// Single block, 512 threads, bitonic over 1024 packed u32 (key<<10 | idx).
// Any permutation is CORRECT (per-roi math independent); sorting only adds
// L2 locality when combined with the XCD chunk swizzle in the gather.
// ---------------------------------------------------------------------------
__global__ __launch_bounds__(512) void sort_rois(const float* __restrict__ rois,
                                                 int* __restrict__ perm) {
  __shared__ unsigned a[1024];
  int t = threadIdx.x;
  for (int i = t; i < 1024; i += 512) {
    unsigned packed;
    if (i < Nroi) {
      const float* r = rois + (size_t)i * 6;
      int b = (int)r[0];
      int tx = min(max((int)(r[1] * SCALE * (1.0f / 16.0f)), 0), 31);
      int ty = min(max((int)(r[2] * SCALE * (1.0f / 16.0f)), 0), 31);
      unsigned m = 0;
#pragma unroll
      for (int bit = 0; bit < 5; ++bit) {
        m |= (((tx >> bit) & 1u) << (2 * bit)) | (((ty >> bit) & 1u) << (2 * bit + 1));
      }
      unsigned key = ((unsigned)b << 10) | m;  // 11 bits
      packed = (key << 10) | (unsigned)i;      // 21 bits total
    } else {
      packed = 0xFFFFFC00u | (unsigned)i;      // pad: sorts to the end
    }
    a[i] = packed;
  }
  for (int k = 2; k <= 1024; k <<= 1) {
    for (int j = k >> 1; j > 0; j >>= 1) {
      __syncthreads();
      int i = ((t & ~(j - 1)) << 1) | (t & (j - 1));
      bool up = ((i & k) == 0);
      unsigned x = a[i], y = a[i + j];
      if ((x > y) == up) {
        a[i] = y;
        a[i + j] = x;
      }
    }
  }
  __syncthreads();
  for (int i = t; i < Nroi; i += 512) perm[i] = (int)(a[i] & 1023u);
}

// ---------------------------------------------------------------------------
// Kernel 1 v3 (unchanged): transpose+downconvert feats (B,C,P) f32 -> (B,P,C) bf16.
// ---------------------------------------------------------------------------
constexpr int TPX = 64, TCH = 64, LP = TPX + 1;
__global__ __launch_bounds__(256) void transpose_bf16(const float* __restrict__ feats,
                                                      unsigned short* __restrict__ ft) {
  __shared__ float tile[TCH * LP];
  int p0 = blockIdx.x * TPX;
  int c0 = blockIdx.y * TCH;
  int b = blockIdx.z;
  int t = threadIdx.x;
  int px4 = t & 15, ch = t >> 4;
#pragma unroll
  for (int i = 0; i < 4; ++i) {
    int c = ch + 16 * i;
    const float4 v = *(const float4*)(feats + ((size_t)b * Cn + c0 + c) * HWn + p0 + px4 * 4);
    tile[c * LP + px4 * 4 + 0] = v.x;
    tile[c * LP + px4 * 4 + 1] = v.y;
    tile[c * LP + px4 * 4 + 2] = v.z;
    tile[c * LP + px4 * 4 + 3] = v.w;
  }
  __syncthreads();
  int o = t & 7;     // channel oct (8 ch = 16 B bf16)
  int px8 = t >> 3;  // 0..31
#pragma unroll
  for (int pass = 0; pass < 2; ++pass) {
    int p = px8 + 32 * pass;
    uint4 w4;
    w4.x = bf16pack(tile[(o * 8 + 0) * LP + p], tile[(o * 8 + 1) * LP + p]);
    w4.y = bf16pack(tile[(o * 8 + 2) * LP + p], tile[(o * 8 + 3) * LP + p]);
    w4.z = bf16pack(tile[(o * 8 + 4) * LP + p], tile[(o * 8 + 5) * LP + p]);
    w4.w = bf16pack(tile[(o * 8 + 6) * LP + p], tile[(o * 8 + 7) * LP + p]);
    *(uint4*)((char*)ft + (((size_t)b * HWn + p0 + p) * Cn + c0 + o * 8) * 2) = w4;
  }
}

// ---------------------------------------------------------------------------
// Kernel 2 v8: v7 body + spatially-sorted roi assignment with XCD chunking.
// Block bid processes roi perm[(bid&7)*125 + (bid>>3)]: blocks with equal
// bid&7 land on the same XCD (round-robin dispatch) and enumerate 125
// CONSECUTIVE spatially-sorted rois -> concurrent rois per XCD overlap in
// the feature map -> ft reads become L2 hits instead of L3 streams.
// ---------------------------------------------------------------------------
constexpr int HB1 = 25;  // bins per staging phase (25 then 24)
__global__ __launch_bounds__(256, 4) void roi_gather8(const unsigned short* __restrict__ ft,
                                                      const float* __restrict__ rois,
                                                      const int* __restrict__ perm,
                                                      float* __restrict__ out) {
  __shared__ int4 s_m[NP];   // {idxB, dxB, dyB, 0} byte offsets into bf16 ft
  __shared__ float4 s_w[NP];
  __shared__ __align__(16) float s_out[Cn * HB1];  // 25600 B
  int bid = blockIdx.x;
  int n = perm[((bid & 7) * (Nroi / 8)) + (bid >> 3)];
  const float* r = rois + (size_t)n * 6;
  int t = threadIdx.x;
  if (t < NP) {
    int idx, dx, dy;
    float4 w;
    compute_desc(r, t, idx, dx, dy, w);
    s_m[t] = make_int4(idx * (Cn * 2), dx * (Cn * 2), dy * (Cn * 2), 0);
    s_w[t] = w;
  }
  __syncthreads();
  int b = (int)r[0];
  int lane = t & 63;
  int wv = t >> 6;     // wave id 0..3
  int k = lane & 31;   // channel chunk: channels k*8 .. k*8+7
  int q = lane >> 5;   // x corner: 0 = x_low, 1 = x_high
  const char* fb = (const char*)ft + (size_t)b * HWn * Cn * 2 + (size_t)k * 16;
  float* ob = out + (size_t)n * Cn * NBIN;

#pragma unroll 1
  for (int ph = 0; ph < 2; ++ph) {
    int b0 = ph ? HB1 : 0;
    int b1 = ph ? NBIN : HB1;
    for (int bin = b0 + wv; bin < b1; bin += 4) {
      int bi = bin / OW;
      int bj = bin - bi * OW;
      int p00 = (bi * 2) * NS + bj * 2;
      float acc0 = 0.f, acc1 = 0.f, acc2 = 0.f, acc3 = 0.f;
      float acc4 = 0.f, acc5 = 0.f, acc6 = 0.f, acc7 = 0.f;
#pragma unroll
      for (int s = 0; s < 4; ++s) {
        int p = p00 + (s >> 1) * NS + (s & 1);
        int4 m = s_m[p];   // wave-uniform broadcast
        float4 w = s_w[p];
        const char* A = fb + m.x + q * m.y;     // this lane's x-corner column
        uint4 vlo = *(const uint4*)(A);          // row y_low
        uint4 vhi = *(const uint4*)(A + m.z);    // row y_high
        float wlo = q ? w.y : w.x;
        float whi = q ? w.w : w.z;
#define ACC(vv, ww)                                                        \
        acc0 += (ww) * __uint_as_float((vv).x << 16);                      \
        acc1 += (ww) * __uint_as_float((vv).x & 0xffff0000u);              \
        acc2 += (ww) * __uint_as_float((vv).y << 16);                      \
        acc3 += (ww) * __uint_as_float((vv).y & 0xffff0000u);              \
        acc4 += (ww) * __uint_as_float((vv).z << 16);                      \
        acc5 += (ww) * __uint_as_float((vv).z & 0xffff0000u);              \
        acc6 += (ww) * __uint_as_float((vv).w << 16);                      \
        acc7 += (ww) * __uint_as_float((vv).w & 0xffff0000u);
        ACC(vlo, wlo)
        ACC(vhi, whi)
#undef ACC
      }
      // combine x_low/x_high halves (partner lane = lane^32)
      acc0 += __shfl_xor(acc0, 32);
      acc1 += __shfl_xor(acc1, 32);
      acc2 += __shfl_xor(acc2, 32);
      acc3 += __shfl_xor(acc3, 32);
      acc4 += __shfl_xor(acc4, 32);
      acc5 += __shfl_xor(acc5, 32);
      acc6 += __shfl_xor(acc6, 32);
      acc7 += __shfl_xor(acc7, 32);
      if (q == 0) {
        int col = bin - b0;
        s_out[(k * 8 + 0) * HB1 + col] = acc0 * 0.25f;
        s_out[(k * 8 + 1) * HB1 + col] = acc1 * 0.25f;
        s_out[(k * 8 + 2) * HB1 + col] = acc2 * 0.25f;
        s_out[(k * 8 + 3) * HB1 + col] = acc3 * 0.25f;
        s_out[(k * 8 + 4) * HB1 + col] = acc4 * 0.25f;
        s_out[(k * 8 + 5) * HB1 + col] = acc5 * 0.25f;
        s_out[(k * 8 + 6) * HB1 + col] = acc6 * 0.25f;
        s_out[(k * 8 + 7) * HB1 + col] = acc7 * 0.25f;
      }
    }
    __syncthreads();
    // write-out this phase's columns
    if (ph == 0) {
#pragma unroll
      for (int i2 = 0; i2 < 25; ++i2) {
        int idx = t + 256 * i2;      // < 6400
        int c = idx / 25;
        int bn = idx - c * 25;
        ob[c * NBIN + bn] = s_out[idx];
      }
    } else {
#pragma unroll
      for (int i2 = 0; i2 < 24; ++i2) {
        int idx = t + 256 * i2;      // < 6144
        int c = idx / 24;
        int bn = idx - c * 24;
        ob[c * NBIN + HB1 + bn] = s_out[c * HB1 + bn];
      }
    }
    __syncthreads();
  }
}

// ---------------------------------------------------------------------------
// Fallback (if workspace too small): direct gather from (B,C,H,W), f32.
// ---------------------------------------------------------------------------
__global__ __launch_bounds__(256) void roi_direct(const float* __restrict__ feats,
                                                  const float* __restrict__ rois,
                                                  float* __restrict__ out) {
  __shared__ int s_idx[NP];
  __shared__ int s_dx[NP];
  __shared__ int s_dy[NP];
  __shared__ float4 s_w[NP];
  int n = blockIdx.x;
  const float* r = rois + (size_t)n * 6;
  int t = threadIdx.x;
  if (t < NP) {
    int idx, dx, dy;
    float4 w;
    compute_desc(r, t, idx, dx, dy, w);
    s_idx[t] = idx;
    s_dx[t] = dx;
    s_dy[t] = dy;
    s_w[t] = w;
  }
  __syncthreads();
  int b = (int)r[0];
  const float* f = feats + ((size_t)b * Cn + t) * HWn;
  float* o = out + ((size_t)n * Cn + t) * NBIN;
  for (int bi = 0; bi < OH; ++bi) {
    for (int bj = 0; bj < OW; ++bj) {
      float acc = 0.0f;
#pragma unroll
      for (int s = 0; s < 4; ++s) {
        int p = (bi * 2 + (s >> 1)) * NS + bj * 2 + (s & 1);
        int idx = s_idx[p];
        int dx = s_dx[p];
        int dy = s_dy[p];
        float4 w = s_w[p];
        acc += w.x * f[idx] + w.y * f[idx + dx] + w.z * f[idx + dy] + w.w * f[idx + dy + dx];
      }
      o[bi * OW + bj] = acc * 0.25f;
    }
  }
}

extern "C" void kernel_launch(void* const* d_in, const int* in_sizes, int n_in,
                              void* d_out, int out_size, void* d_ws, size_t ws_size,
                              hipStream_t stream) {
  const float* feats = (const float*)d_in[0];  // (2,256,200,304) f32
  const float* rois = (const float*)d_in[1];   // (1000,6) f32
  float* out = (float*)d_out;                  // (1000,256,7,7) f32

  size_t ftBytes = (size_t)Bn * HWn * Cn * sizeof(unsigned short);  // ~62.3 MB
  size_t need = ftBytes + 4096;
  if (ws_size >= need) {
    unsigned short* ft = (unsigned short*)d_ws;
    int* perm = (int*)((char*)d_ws + ftBytes);
    sort_rois<<<1, 512, 0, stream>>>(rois, perm);
    transpose_bf16<<<dim3(HWn / TPX, Cn / TCH, Bn), 256, 0, stream>>>(feats, ft);
    roi_gather8<<<dim3(Nroi), 256, 0, stream>>>(ft, rois, perm, out);
  } else {
    roi_direct<<<Nroi, 256, 0, stream>>>(feats, rois, out);
  }
}

// Round 3
// 244.843 us; speedup vs baseline: 1.1494x; 1.1494x over previous
//
#include <hip/hip_runtime.h>
#include <math.h>

// Problem constants (from reference setup_inputs)
constexpr int Bn = 2, Cn = 256, Hn = 200, Wn = 304, Nroi = 1000;
constexpr int OH = 7, OW = 7, SRn = 2;
constexpr int NS = OH * SRn;   // 14 subsample rows/cols
constexpr int NP = NS * NS;    // 196 subsample positions per roi
constexpr int NBIN = OH * OW;  // 49
constexpr int HWn = Hn * Wn;   // 60800
constexpr float SCALE = 0.25f;

// ---------------------------------------------------------------------------
// Per-position sampling descriptor (matches JAX reference arithmetic, f32).
// ---------------------------------------------------------------------------
__device__ __forceinline__ void compute_desc(const float* __restrict__ r, int p,
                                             int& idx, int& dx, int& dyW,
                                             float4& w) {
  float cw = r[1] * SCALE - 0.5f;
  float ch = r[2] * SCALE - 0.5f;
  float rw = r[3] * SCALE;
  float rh = r[4] * SCALE;
  float theta = r[5] * 0.017453292519943295f;  // pi/180
  float cs = cosf(theta), sn = sinf(theta);
  float bin_h = rh * (1.0f / OH);
  float bin_w = rw * (1.0f / OW);
  int ki = p / NS;
  int kj = p - ki * NS;
  float ty = ((float)ki + 0.5f) * (1.0f / SRn);
  float tx = ((float)kj + 0.5f) * (1.0f / SRn);
  float yy = -0.5f * rh + ty * bin_h;
  float xx = -0.5f * rw + tx * bin_w;
  float y = yy * cs - xx * sn + ch;
  float x = yy * sn + xx * cs + cw;
  bool empty = (y < -1.0f) || (y > (float)Hn) || (x < -1.0f) || (x > (float)Wn);
  y = fmaxf(y, 0.0f);
  x = fmaxf(x, 0.0f);
  int yl = min(max((int)floorf(y), 0), Hn - 1);
  int xl = min(max((int)floorf(x), 0), Wn - 1);
  int yh = min(yl + 1, Hn - 1);
  int xh = min(xl + 1, Wn - 1);
  float ly = fminf(fmaxf(y - (float)yl, 0.0f), 1.0f);
  float lx = fminf(fmaxf(x - (float)xl, 0.0f), 1.0f);
  float hy = 1.0f - ly, hx = 1.0f - lx;
  if (empty) {
    w.x = w.y = w.z = w.w = 0.0f;
  } else {
    w.x = hy * hx;
    w.y = hy * lx;
    w.z = ly * hx;
    w.w = ly * lx;
  }
  idx = yl * Wn + xl;
  dx = xh - xl;
  dyW = (yh - yl) * Wn;
}

__device__ __forceinline__ unsigned bf16rne(float f) {
  unsigned u = __float_as_uint(f);
  return (u + 0x7fffu + ((u >> 16) & 1u)) >> 16;
}
__device__ __forceinline__ unsigned bf16pack(float lo, float hi) {
  return bf16rne(lo) | (bf16rne(hi) << 16);
}

// ---------------------------------------------------------------------------
// Kernel 0: spatial sort of roi indices (batch + Morton of 16px center tile).
// Single block, 512 threads, bitonic over 1024 packed u32 (key<<10 | idx).
// ---------------------------------------------------------------------------
__global__ __launch_bounds__(512) void sort_rois(const float* __restrict__ rois,
                                                 int* __restrict__ perm) {
  __shared__ unsigned a[1024];
  int t = threadIdx.x;
  for (int i = t; i < 1024; i += 512) {
    unsigned packed;
    if (i < Nroi) {
      const float* r = rois + (size_t)i * 6;
      int b = (int)r[0];
      int tx = min(max((int)(r[1] * SCALE * (1.0f / 16.0f)), 0), 31);
      int ty = min(max((int)(r[2] * SCALE * (1.0f / 16.0f)), 0), 31);
      unsigned m = 0;
#pragma unroll
      for (int bit = 0; bit < 5; ++bit) {
        m |= (((tx >> bit) & 1u) << (2 * bit)) | (((ty >> bit) & 1u) << (2 * bit + 1));
      }
      unsigned key = ((unsigned)b << 10) | m;  // 11 bits
      packed = (key << 10) | (unsigned)i;      // 21 bits total
    } else {
      packed = 0xFFFFFC00u | (unsigned)i;      // pad: sorts to the end
    }
    a[i] = packed;
  }
  for (int k = 2; k <= 1024; k <<= 1) {
    for (int j = k >> 1; j > 0; j >>= 1) {
      __syncthreads();
      int i = ((t & ~(j - 1)) << 1) | (t & (j - 1));
      bool up = ((i & k) == 0);
      unsigned x = a[i], y = a[i + j];
      if ((x > y) == up) {
        a[i] = y;
        a[i + j] = x;
      }
    }
  }
  __syncthreads();
  for (int i = t; i < Nroi; i += 512) perm[i] = (int)(a[i] & 1023u);
}

// ---------------------------------------------------------------------------
// Kernel 1 v3 (unchanged): transpose+downconvert feats (B,C,P) f32 -> (B,P,C) bf16.
// ---------------------------------------------------------------------------
constexpr int TPX = 64, TCH = 64, LP = TPX + 1;
__global__ __launch_bounds__(256) void transpose_bf16(const float* __restrict__ feats,
                                                      unsigned short* __restrict__ ft) {
  __shared__ float tile[TCH * LP];
  int p0 = blockIdx.x * TPX;
  int c0 = blockIdx.y * TCH;
  int b = blockIdx.z;
  int t = threadIdx.x;
  int px4 = t & 15, ch = t >> 4;
#pragma unroll
  for (int i = 0; i < 4; ++i) {
    int c = ch + 16 * i;
    const float4 v = *(const float4*)(feats + ((size_t)b * Cn + c0 + c) * HWn + p0 + px4 * 4);
    tile[c * LP + px4 * 4 + 0] = v.x;
    tile[c * LP + px4 * 4 + 1] = v.y;
    tile[c * LP + px4 * 4 + 2] = v.z;
    tile[c * LP + px4 * 4 + 3] = v.w;
  }
  __syncthreads();
  int o = t & 7;     // channel oct (8 ch = 16 B bf16)
  int px8 = t >> 3;  // 0..31
#pragma unroll
  for (int pass = 0; pass < 2; ++pass) {
    int p = px8 + 32 * pass;
    uint4 w4;
    w4.x = bf16pack(tile[(o * 8 + 0) * LP + p], tile[(o * 8 + 1) * LP + p]);
    w4.y = bf16pack(tile[(o * 8 + 2) * LP + p], tile[(o * 8 + 3) * LP + p]);
    w4.z = bf16pack(tile[(o * 8 + 4) * LP + p], tile[(o * 8 + 5) * LP + p]);
    w4.w = bf16pack(tile[(o * 8 + 6) * LP + p], tile[(o * 8 + 7) * LP + p]);
    *(uint4*)((char*)ft + (((size_t)b * HWn + p0 + p) * Cn + c0 + o * 8) * 2) = w4;
  }
}

// ---------------------------------------------------------------------------
// Kernel 2 v9: L2-sized active window.
// Grid = 8 XCD x 32 blocks, 512 threads (8 waves) each, 1 block/CU.
// Block j of XCD x processes sorted rois perm[125*x + step*32 + j]:
// at any instant each XCD works on ~32 CONSECUTIVE Morton-sorted rois
// (~2-3 MB unique footprint < 4 MB per-XCD L2) -> the 6.5x pixel reuse
// is captured in L2 instead of re-streaming over the L3/fabric.
// Per-wave body identical to v7/v8 (1024-B contiguous wave-loads,
// shfl_xor(32) x-corner combine); one full-49-bin LDS staging pass.
// ---------------------------------------------------------------------------
constexpr int BPX = 32;   // blocks per XCD
constexpr int SEG = 125;  // rois per XCD segment (1000/8)
__global__ __launch_bounds__(512, 2) void roi_gather9(const unsigned short* __restrict__ ft,
                                                      const float* __restrict__ rois,
                                                      const int* __restrict__ perm,
                                                      float* __restrict__ out) {
  __shared__ int4 s_m[NP];   // {idxB, dxB, dyB, 0} byte offsets into bf16 ft
  __shared__ float4 s_w[NP];
  __shared__ __align__(16) float s_out[Cn * NBIN];  // 50176 B
  int x = blockIdx.x & 7;   // XCD id (round-robin dispatch heuristic)
  int jb = blockIdx.x >> 3; // block within XCD, 0..31
  int t = threadIdx.x;
  int lane = t & 63;
  int wv = t >> 6;          // wave id 0..7
  int k = lane & 31;        // channel chunk: channels k*8 .. k*8+7
  int q = lane >> 5;        // x corner: 0 = x_low, 1 = x_high

  for (int step = 0; step < 4; ++step) {
    int idxr = step * BPX + jb;
    if (idxr >= SEG) break;
    int n = perm[x * SEG + idxr];
    const float* r = rois + (size_t)n * 6;
    if (t < NP) {
      int idx, dx, dy;
      float4 w;
      compute_desc(r, t, idx, dx, dy, w);
      s_m[t] = make_int4(idx * (Cn * 2), dx * (Cn * 2), dy * (Cn * 2), 0);
      s_w[t] = w;
    }
    __syncthreads();
    int b = (int)r[0];
    const char* fb = (const char*)ft + (size_t)b * HWn * Cn * 2 + (size_t)k * 16;

    for (int bin = wv; bin < NBIN; bin += 8) {
      int bi = bin / OW;
      int bj = bin - bi * OW;
      int p00 = (bi * 2) * NS + bj * 2;
      float acc0 = 0.f, acc1 = 0.f, acc2 = 0.f, acc3 = 0.f;
      float acc4 = 0.f, acc5 = 0.f, acc6 = 0.f, acc7 = 0.f;
#pragma unroll
      for (int s = 0; s < 4; ++s) {
        int p = p00 + (s >> 1) * NS + (s & 1);
        int4 m = s_m[p];   // wave-uniform broadcast
        float4 w = s_w[p];
        const char* A = fb + m.x + q * m.y;     // this lane's x-corner column
        uint4 vlo = *(const uint4*)(A);          // row y_low : 1024 B contiguous/wave
        uint4 vhi = *(const uint4*)(A + m.z);    // row y_high: 1024 B contiguous/wave
        float wlo = q ? w.y : w.x;
        float whi = q ? w.w : w.z;
#define ACC(vv, ww)                                                        \
        acc0 += (ww) * __uint_as_float((vv).x << 16);                      \
        acc1 += (ww) * __uint_as_float((vv).x & 0xffff0000u);              \
        acc2 += (ww) * __uint_as_float((vv).y << 16);                      \
        acc3 += (ww) * __uint_as_float((vv).y & 0xffff0000u);              \
        acc4 += (ww) * __uint_as_float((vv).z << 16);                      \
        acc5 += (ww) * __uint_as_float((vv).z & 0xffff0000u);              \
        acc6 += (ww) * __uint_as_float((vv).w << 16);                      \
        acc7 += (ww) * __uint_as_float((vv).w & 0xffff0000u);
        ACC(vlo, wlo)
        ACC(vhi, whi)
#undef ACC
      }
      // combine x_low/x_high halves (partner lane = lane^32)
      acc0 += __shfl_xor(acc0, 32);
      acc1 += __shfl_xor(acc1, 32);
      acc2 += __shfl_xor(acc2, 32);
      acc3 += __shfl_xor(acc3, 32);
      acc4 += __shfl_xor(acc4, 32);
      acc5 += __shfl_xor(acc5, 32);
      acc6 += __shfl_xor(acc6, 32);
      acc7 += __shfl_xor(acc7, 32);
      if (q == 0) {
        s_out[(k * 8 + 0) * NBIN + bin] = acc0 * 0.25f;
        s_out[(k * 8 + 1) * NBIN + bin] = acc1 * 0.25f;
        s_out[(k * 8 + 2) * NBIN + bin] = acc2 * 0.25f;
        s_out[(k * 8 + 3) * NBIN + bin] = acc3 * 0.25f;
        s_out[(k * 8 + 4) * NBIN + bin] = acc4 * 0.25f;
        s_out[(k * 8 + 5) * NBIN + bin] = acc5 * 0.25f;
        s_out[(k * 8 + 6) * NBIN + bin] = acc6 * 0.25f;
        s_out[(k * 8 + 7) * NBIN + bin] = acc7 * 0.25f;
      }
    }
    __syncthreads();
    // Coalesced write-out: 256ch x 49bin floats, linear.
    float* ob = out + (size_t)n * Cn * NBIN;
    for (int i = t; i < Cn * NBIN; i += 512) ob[i] = s_out[i];
    __syncthreads();
  }
}

// ---------------------------------------------------------------------------
// Fallback (if workspace too small): direct gather from (B,C,H,W), f32.
// ---------------------------------------------------------------------------
__global__ __launch_bounds__(256) void roi_direct(const float* __restrict__ feats,
                                                  const float* __restrict__ rois,
                                                  float* __restrict__ out) {
  __shared__ int s_idx[NP];
  __shared__ int s_dx[NP];
  __shared__ int s_dy[NP];
  __shared__ float4 s_w[NP];
  int n = blockIdx.x;
  const float* r = rois + (size_t)n * 6;
  int t = threadIdx.x;
  if (t < NP) {
    int idx, dx, dy;
    float4 w;
    compute_desc(r, t, idx, dx, dy, w);
    s_idx[t] = idx;
    s_dx[t] = dx;
    s_dy[t] = dy;
    s_w[t] = w;
  }
  __syncthreads();
  int b = (int)r[0];
  const float* f = feats + ((size_t)b * Cn + t) * HWn;
  float* o = out + ((size_t)n * Cn + t) * NBIN;
  for (int bi = 0; bi < OH; ++bi) {
    for (int bj = 0; bj < OW; ++bj) {
      float acc = 0.0f;
#pragma unroll
      for (int s = 0; s < 4; ++s) {
        int p = (bi * 2 + (s >> 1)) * NS + bj * 2 + (s & 1);
        int idx = s_idx[p];
        int dx = s_dx[p];
        int dy = s_dy[p];
        float4 w = s_w[p];
        acc += w.x * f[idx] + w.y * f[idx + dx] + w.z * f[idx + dy] + w.w * f[idx + dy + dx];
      }
      o[bi * OW + bj] = acc * 0.25f;
    }
  }
}

extern "C" void kernel_launch(void* const* d_in, const int* in_sizes, int n_in,
                              void* d_out, int out_size, void* d_ws, size_t ws_size,
                              hipStream_t stream) {
  const float* feats = (const float*)d_in[0];  // (2,256,200,304) f32
  const float* rois = (const float*)d_in[1];   // (1000,6) f32
  float* out = (float*)d_out;                  // (1000,256,7,7) f32

  size_t ftBytes = (size_t)Bn * HWn * Cn * sizeof(unsigned short);  // ~62.3 MB
  size_t need = ftBytes + 4096;
  if (ws_size >= need) {
    unsigned short* ft = (unsigned short*)d_ws;
    int* perm = (int*)((char*)d_ws + ftBytes);
    sort_rois<<<1, 512, 0, stream>>>(rois, perm);
    transpose_bf16<<<dim3(HWn / TPX, Cn / TCH, Bn), 256, 0, stream>>>(feats, ft);
    roi_gather9<<<dim3(8 * BPX), 512, 0, stream>>>(ft, rois, perm, out);
  } else {
    roi_direct<<<Nroi, 256, 0, stream>>>(feats, rois, out);
  }
}